// Round 7
// baseline (424.177 us; speedup 1.0000x reference)
//
#include <hip/hip_runtime.h>

typedef unsigned short u16;
typedef unsigned int   u32;

typedef short    short8 __attribute__((ext_vector_type(8)));
typedef __bf16   bf16x8 __attribute__((ext_vector_type(8)));
typedef _Float16 half8  __attribute__((ext_vector_type(8)));
typedef float    f32x4  __attribute__((ext_vector_type(4)));

#define S_LEN   2048
#define DM      1024
#define NHEAD   16
#define DK      64
#define BH_TOT  64
#define M_TOK   8192
#define KDIM    1024

// ---------- helpers ----------
__device__ __forceinline__ u16 f2bf(float f) {
    u32 u = __builtin_bit_cast(u32, f);
    u += 0x7FFFu + ((u >> 16) & 1u);      // RNE
    return (u16)(u >> 16);
}
__device__ __forceinline__ float bf2f(u16 h) {
    u32 u = ((u32)h) << 16;
    return __builtin_bit_cast(float, u);
}
__device__ __forceinline__ f32x4 mfma_bf16(short8 a, short8 b, f32x4 c) {
    return __builtin_amdgcn_mfma_f32_16x16x32_bf16(
        __builtin_bit_cast(bf16x8, a), __builtin_bit_cast(bf16x8, b), c, 0, 0, 0);
}
__device__ __forceinline__ f32x4 mfma_f16(half8 a, half8 b, f32x4 c) {
    return __builtin_amdgcn_mfma_f32_16x16x32_f16(a, b, c, 0, 0, 0);
}
__device__ __forceinline__ u32 pk_f16(float a, float b) {
    return __builtin_bit_cast(u32, __builtin_amdgcn_cvt_pkrtz(a, b));
}
__device__ __forceinline__ void gl_lds16(const void* g, void* l) {
    __builtin_amdgcn_global_load_lds(
        (const __attribute__((address_space(1))) u32*)g,
        (__attribute__((address_space(3))) u32*)l, 16, 0, 0);
}
// raw barrier / waitcnt (flash pipeline): no compiler vmcnt(0) drain
__device__ __forceinline__ void bar_raw() { asm volatile("s_barrier" ::: "memory"); }
__device__ __forceinline__ void wait_vm4() { asm volatile("s_waitcnt vmcnt(4)" ::: "memory"); }
__device__ __forceinline__ void wait_vm0() { asm volatile("s_waitcnt vmcnt(0)" ::: "memory"); }

// K-row permutation for flash: LDS row rc holds global k-row perm_inv(rc) so that
// PV A-frags are in-lane after S^T: k'(nt,quad,r)=32*(nt>>1)+8*quad+4*(nt&1)+r
__device__ __forceinline__ int perm_inv(int rc) {
    const int nt = rc >> 4, mid = (rc >> 2) & 3, r = rc & 3;
    return 32 * (nt >> 1) + 8 * mid + 4 * (nt & 1) + r;
}

// ---------- fp32 -> bf16 convert (x4 vectorized) ----------
__global__ void cvt_bf16_v4(const float4* __restrict__ in, uint2* __restrict__ out, int n4) {
    int i = blockIdx.x * 256 + threadIdx.x;
    if (i >= n4) return;
    float4 f = in[i];
    uint2 o;
    o.x = (u32)f2bf(f.x) | ((u32)f2bf(f.y) << 16);
    o.y = (u32)f2bf(f.z) | ((u32)f2bf(f.w) << 16);
    out[i] = o;
}

// ---------- RoPE (in-place on Q,K; one u32 = one even/odd pair) ----------
__global__ void rope_qk(u16* __restrict__ Qb, u16* __restrict__ Kb) {
    int idx = blockIdx.x * 256 + threadIdx.x;
    const int PER = BH_TOT * S_LEN * 32;
    u16* T = (idx < PER) ? Qb : Kb;
    int i2 = (idx < PER) ? idx : idx - PER;
    int i  = i2 & 31;
    int s  = (i2 >> 5) & 2047;
    int bh = i2 >> 16;
    u32* p = (u32*)T + (size_t)(bh * S_LEN + s) * 32 + i;
    u32 v = *p;
    float e = bf2f((u16)(v & 0xFFFF));
    float o = bf2f((u16)(v >> 16));
    float inv = expf(-(float)i * 0.287823136624255f);   // 10000^(-i/32)
    float ang = (float)s * inv;
    float sn = sinf(ang), cs = cosf(ang);
    float e2 = e * cs - o * sn;
    float o2 = e * sn + o * cs;
    *p = (u32)f2bf(e2) | ((u32)f2bf(o2) << 16);
}

// ---------- register-pipelined NT GEMM (no LDS, no barriers) ----------
// C[m][n] = sum_k A[m][k]*W[n][k]. BM=BN=128, 4 waves, wave tile 64x64 (4x4 of
// 16x16x32). Fragments loaded DIRECTLY from global (L1/L2-served; sibling wave
// provides 2x reuse through L1), double-buffered in registers one k-step ahead.
// 8 per-lane base pointers + immediate offsets (kt*64 <= 1984 fits 13-bit field)
// -> zero address VALU, zero barriers, compiler emits partial vmcnt waits.
// MODE 0: N=3072 fused QKV epilogue (Q,K bf16 -> [BH][S][64], V fp16 -> [BH][64][S])
// MODE 1: plain fp32 store
template <int MODE>
__global__ __launch_bounds__(256)
void gemm_reg(const u16* __restrict__ A, const u16* __restrict__ Bw,
              u16* __restrict__ oQ, u16* __restrict__ oK, u16* __restrict__ oVt,
              float* __restrict__ oF) {
    const int tid  = threadIdx.x;
    const int wave = tid >> 6, lane = tid & 63;
    const int quad = lane >> 4, l15 = lane & 15;
    const int wr = wave >> 1, wc = wave & 1;
    const int mbase = blockIdx.y * 128;
    const int nbase = blockIdx.x * 128;

    const char* pA[4];
    const char* pB[4];
#pragma unroll
    for (int i = 0; i < 4; i++) {
        pA[i] = (const char*)(A  + (size_t)(mbase + wr * 64 + i * 16 + l15) * KDIM + quad * 8);
        pB[i] = (const char*)(Bw + (size_t)(nbase + wc * 64 + i * 16 + l15) * KDIM + quad * 8);
    }

    f32x4 acc[4][4];
#pragma unroll
    for (int i = 0; i < 4; i++)
#pragma unroll
        for (int j = 0; j < 4; j++) acc[i][j] = (f32x4)0.0f;

    short8 a[2][4], b[2][4];
#pragma unroll
    for (int i = 0; i < 4; i++) {
        a[0][i] = *(const short8*)pA[i];
        b[0][i] = *(const short8*)pB[i];
    }
#pragma unroll
    for (int kt = 0; kt < 32; kt++) {
        const int cur = kt & 1, nxt = cur ^ 1;
        if (kt < 31) {
            const int off = (kt + 1) * 64;          // compile-time under full unroll
#pragma unroll
            for (int i = 0; i < 4; i++) {
                a[nxt][i] = *(const short8*)(pA[i] + off);
                b[nxt][i] = *(const short8*)(pB[i] + off);
            }
        }
#pragma unroll
        for (int mt = 0; mt < 4; mt++)
#pragma unroll
            for (int nt = 0; nt < 4; nt++)
                acc[mt][nt] = mfma_bf16(a[cur][mt], b[cur][nt], acc[mt][nt]);
    }

    // epilogue. C layout: col = l15, row = quad*4 + reg
#pragma unroll
    for (int mt = 0; mt < 4; mt++) {
#pragma unroll
        for (int nt = 0; nt < 4; nt++) {
            const int n  = nbase + wc * 64 + nt * 16 + l15;
            const int mb = mbase + wr * 64 + mt * 16 + quad * 4;
            f32x4 v = acc[mt][nt];
            if (MODE == 0) {
                const int proj = n >> 10;       // 0=Q 1=K 2=V
                const int e = n & 1023;
                const int h = e >> 6, d = e & 63;
                if (proj == 2) {
                    const int b_ = mb >> 11, s = mb & 2047;
                    const int bh = b_ * NHEAD + h;
                    uint2 pk;                           // fp16 V (RTZ)
                    pk.x = pk_f16(v[0], v[1]);
                    pk.y = pk_f16(v[2], v[3]);
                    *(uint2*)&oVt[((size_t)bh * DK + d) * S_LEN + s] = pk;
                } else {
                    u16* dst = (proj == 0) ? oQ : oK;
#pragma unroll
                    for (int r = 0; r < 4; r++) {
                        const int m = mb + r;
                        const int b_ = m >> 11, s = m & 2047;
                        const int bh = b_ * NHEAD + h;
                        dst[((size_t)bh * S_LEN + s) * DK + d] = f2bf(v[r]);
                    }
                }
            } else {
#pragma unroll
                for (int r = 0; r < 4; r++)
                    oF[(size_t)(mb + r) * DM + n] = v[r];
            }
        }
    }
}

// ---------- causal flash attention (S^T form, P in-register, double-buffered pipeline) ----------
// grid (BH=64, 32): bh = blockIdx.x so all 32 q-blocks of a head share an XCD
// (id mod 8 == bh mod 8); qt = 31-blockIdx.y (heavy tiles dispatch first).
__global__ __launch_bounds__(256)
void flash_attn(const u16* __restrict__ Q, const u16* __restrict__ K,
                const u16* __restrict__ Vt, u16* __restrict__ Oc) {
    __shared__ u16 Ks[2][64 * 64];     // permuted k-rows, XOR chunk swizzle
    __shared__ u16 Vs[2][64 * 64];     // [d][s], XOR chunk swizzle
    const int qt = 31 - (int)blockIdx.y;
    const int bh = blockIdx.x;
    const int tid  = threadIdx.x;
    const int wave = tid >> 6, lane = tid & 63;
    const int quad = lane >> 4, l15 = lane & 15;
    const int x7 = l15 & 7;
    const size_t headQK = (size_t)bh * S_LEN * DK;
    const size_t headVt = (size_t)bh * DK * S_LEN;
    const int b = bh >> 4, h = bh & 15;
    const float SCL = 0.18033688011112042f;   // (1/8) * log2(e)

    half8 ones;
#pragma unroll
    for (int j = 0; j < 8; j++) ones[j] = (_Float16)1.0f;

    const int rwl  = lane >> 3;                 // row within 8-row slab
    const int scol = (lane & 7) ^ rwl;          // XOR-swizzled chunk column
    const int rc0 = wave * 16 + rwl, rc1 = rc0 + 8;
    const u16* gK0 = K  + headQK + (size_t)perm_inv(rc0) * DK + scol * 8;
    const u16* gK1 = K  + headQK + (size_t)perm_inv(rc1) * DK + scol * 8;
    const u16* gV0 = Vt + headVt + (size_t)rc0 * S_LEN + scol * 8;
    const u16* gV1 = Vt + headVt + (size_t)rc1 * S_LEN + scol * 8;
    const int ldsOff = wave * 2048 + lane * 16;
    const int koff0 = (quad ^ x7) * 8;          // dk chunk 0..31, swizzled
    const int koff1 = ((4 + quad) ^ x7) * 8;    // dk chunk 32..63

    // Q B-fragments
    const int qrow = qt * 64 + wave * 16 + l15;
    const short8 qf0 = *(const short8*)&Q[headQK + (size_t)qrow * DK + quad * 8];
    const short8 qf1 = *(const short8*)&Q[headQK + (size_t)qrow * DK + 32 + quad * 8];

    float m_st = -__builtin_inff();
    f32x4 lacc = (f32x4)0.0f;
    f32x4 oacc[4];
#pragma unroll
    for (int n = 0; n < 4; n++) oacc[n] = (f32x4)0.0f;

    // prologue: stage tile 0 into buffer 0
    gl_lds16(gK0, (char*)Ks[0] + ldsOff);
    gl_lds16(gK1, (char*)Ks[0] + ldsOff + 1024);
    gl_lds16(gV0, (char*)Vs[0] + ldsOff);
    gl_lds16(gV1, (char*)Vs[0] + ldsOff + 1024);

    for (int kt = 0; kt <= qt; kt++) {
        const int cur = kt & 1, nxt = cur ^ 1;
        bar_raw();   // (A) everyone done reading buf[nxt]
        {            // prefetch tile kt+1 (clamped dummy on last iter)
            const int ktn = (kt < qt) ? kt + 1 : qt;
            gl_lds16(gK0 + (size_t)ktn * 64 * DK, (char*)Ks[nxt] + ldsOff);
            gl_lds16(gK1 + (size_t)ktn * 64 * DK, (char*)Ks[nxt] + ldsOff + 1024);
            gl_lds16(gV0 + ktn * 64,              (char*)Vs[nxt] + ldsOff);
            gl_lds16(gV1 + ktn * 64,              (char*)Vs[nxt] + ldsOff + 1024);
        }
        wait_vm4();  // tile kt landed; prefetch stays in flight
        bar_raw();   // (B) all waves' tile-kt staging visible

        // S^T scores (log2-scaled): A = K_perm rows, B = Q
        f32x4 sc[4];
#pragma unroll
        for (int nt = 0; nt < 4; nt++) {
            const int rb = (nt * 16 + l15) * 64;
            short8 kf0 = *(const short8*)&Ks[cur][rb + koff0];
            short8 kf1 = *(const short8*)&Ks[cur][rb + koff1];
            f32x4 z = (f32x4)0.0f;
            z = mfma_bf16(kf0, qf0, z);
            z = mfma_bf16(kf1, qf1, z);
#pragma unroll
            for (int r = 0; r < 4; r++) z[r] *= SCL;
            sc[nt] = z;
        }
        if (kt == qt) {   // diagonal tile causal mask: k' > wave*16 + l15
            const int qloc = wave * 16 + l15;
#pragma unroll
            for (int nt = 0; nt < 4; nt++) {
                const int kb = 32 * (nt >> 1) + 8 * quad + 4 * (nt & 1);
#pragma unroll
                for (int r = 0; r < 4; r++)
                    if (kb + r > qloc) sc[nt][r] = -__builtin_inff();
            }
        }
        // row max: in-lane over 16, then across quads
        float mx0 = fmaxf(fmaxf(sc[0][0], sc[0][1]), fmaxf(sc[0][2], sc[0][3]));
        float mx1 = fmaxf(fmaxf(sc[1][0], sc[1][1]), fmaxf(sc[1][2], sc[1][3]));
        float mx2 = fmaxf(fmaxf(sc[2][0], sc[2][1]), fmaxf(sc[2][2], sc[2][3]));
        float mx3 = fmaxf(fmaxf(sc[3][0], sc[3][1]), fmaxf(sc[3][2], sc[3][3]));
        float mx = fmaxf(fmaxf(mx0, mx1), fmaxf(mx2, mx3));
        mx = fmaxf(mx, __shfl_xor(mx, 16));
        mx = fmaxf(mx, __shfl_xor(mx, 32));
        const float mn = fmaxf(m_st, mx);
        const float alpha = __builtin_amdgcn_exp2f(m_st - mn);
        m_st = mn;
        // P = exp2(sc - m): in-place, then pack to fp16 A-frags (in-lane)
#pragma unroll
        for (int nt = 0; nt < 4; nt++)
#pragma unroll
            for (int r = 0; r < 4; r++)
                sc[nt][r] = __builtin_amdgcn_exp2f(sc[nt][r] - m_st);
        u32 pw[8];
        pw[0] = pk_f16(sc[0][0], sc[0][1]); pw[1] = pk_f16(sc[0][2], sc[0][3]);
        pw[2] = pk_f16(sc[1][0], sc[1][1]); pw[3] = pk_f16(sc[1][2], sc[1][3]);
        pw[4] = pk_f16(sc[2][0], sc[2][1]); pw[5] = pk_f16(sc[2][2], sc[2][3]);
        pw[6] = pk_f16(sc[3][0], sc[3][1]); pw[7] = pk_f16(sc[3][2], sc[3][3]);
        half8 pf0 = __builtin_bit_cast(half8, *(uint4*)&pw[0]);
        half8 pf1 = __builtin_bit_cast(half8, *(uint4*)&pw[4]);
        // alpha broadcast for C-layout rows quad*4+r (src lane = quad*16 + quad*4+r)
        float alr[4];
#pragma unroll
        for (int r = 0; r < 4; r++) alr[r] = __shfl(alpha, quad * 20 + r);
#pragma unroll
        for (int n = 0; n < 4; n++)
#pragma unroll
            for (int r = 0; r < 4; r++) oacc[n][r] *= alr[r];
#pragma unroll
        for (int r = 0; r < 4; r++) lacc[r] *= alr[r];
        // PV + row-sum (fp16)
#pragma unroll
        for (int c = 0; c < 2; c++) {
            const half8 pf = c ? pf1 : pf0;
            lacc = mfma_f16(pf, ones, lacc);
            const int voff = ((c * 4 + quad) ^ x7) * 8;
#pragma unroll
            for (int nt2 = 0; nt2 < 4; nt2++) {
                half8 vf = __builtin_bit_cast(half8,
                    *(const short8*)&Vs[cur][(nt2 * 16 + l15) * 64 + voff]);
                oacc[nt2] = mfma_f16(pf, vf, oacc[nt2]);
            }
        }
    }
    wait_vm0();   // drain dangling dummy prefetch before exit

    // epilogue: rows quad*4+r, cols l15
#pragma unroll
    for (int r = 0; r < 4; r++) {
        const float inv = 1.0f / lacc[r];
        const int s = qt * 64 + wave * 16 + quad * 4 + r;
#pragma unroll
        for (int nt2 = 0; nt2 < 4; nt2++)
            Oc[((size_t)(b * S_LEN + s)) * DM + h * 64 + nt2 * 16 + l15] =
                f2bf(oacc[nt2][r] * inv);
    }
}

// ---------- workspace layout (u16 elements) ----------
#define OFF_XBF  ((size_t)0)
#define OFF_WCAT ((size_t)8388608)
#define OFF_WO   ((size_t)11534336)
#define OFF_QB   ((size_t)12582912)
#define OFF_KB   ((size_t)20971520)
#define OFF_VT   ((size_t)29360128)

extern "C" void kernel_launch(void* const* d_in, const int* in_sizes, int n_in,
                              void* d_out, int out_size, void* d_ws, size_t ws_size,
                              hipStream_t stream) {
    const float* x  = (const float*)d_in[0];
    const float* Wq = (const float*)d_in[1];
    const float* Wk = (const float*)d_in[2];
    const float* Wv = (const float*)d_in[3];
    const float* Wo = (const float*)d_in[4];
    u16* ws  = (u16*)d_ws;
    u16* XBF = ws + OFF_XBF;
    u16* WCA = ws + OFF_WCAT;
    u16* WOB = ws + OFF_WO;
    u16* QB  = ws + OFF_QB;
    u16* KB  = ws + OFF_KB;
    u16* VT  = ws + OFF_VT;
    u16* AT  = XBF;   // reuse

    cvt_bf16_v4<<<8192, 256, 0, stream>>>((const float4*)x,  (uint2*)XBF, 2097152);
    cvt_bf16_v4<<<1024, 256, 0, stream>>>((const float4*)Wq, (uint2*)(WCA),            262144);
    cvt_bf16_v4<<<1024, 256, 0, stream>>>((const float4*)Wk, (uint2*)(WCA + 1048576),  262144);
    cvt_bf16_v4<<<1024, 256, 0, stream>>>((const float4*)Wv, (uint2*)(WCA + 2097152),  262144);
    cvt_bf16_v4<<<1024, 256, 0, stream>>>((const float4*)Wo, (uint2*)WOB, 262144);

    gemm_reg<0><<<dim3(24, 64), 256, 0, stream>>>(XBF, WCA, QB, KB, VT, nullptr);
    rope_qk<<<32768, 256, 0, stream>>>(QB, KB);
    flash_attn<<<dim3(64, 32), 256, 0, stream>>>(QB, KB, VT, AT);
    gemm_reg<1><<<dim3(8, 64), 256, 0, stream>>>(AT, WOB, nullptr, nullptr, nullptr,
                                                 (float*)d_out);
}

// Round 8
// 277.233 us; speedup vs baseline: 1.5300x; 1.5300x over previous
//
#include <hip/hip_runtime.h>

typedef unsigned short u16;
typedef unsigned int   u32;

typedef short    short8 __attribute__((ext_vector_type(8)));
typedef __bf16   bf16x8 __attribute__((ext_vector_type(8)));
typedef _Float16 half8  __attribute__((ext_vector_type(8)));
typedef float    f32x4  __attribute__((ext_vector_type(4)));

#define S_LEN   2048
#define DM      1024
#define NHEAD   16
#define DK      64
#define BH_TOT  64
#define M_TOK   8192
#define KDIM    1024

// ---------- helpers ----------
__device__ __forceinline__ u16 f2bf(float f) {
    u32 u = __builtin_bit_cast(u32, f);
    u += 0x7FFFu + ((u >> 16) & 1u);      // RNE
    return (u16)(u >> 16);
}
__device__ __forceinline__ float bf2f(u16 h) {
    u32 u = ((u32)h) << 16;
    return __builtin_bit_cast(float, u);
}
__device__ __forceinline__ f32x4 mfma_bf16(short8 a, short8 b, f32x4 c) {
    return __builtin_amdgcn_mfma_f32_16x16x32_bf16(
        __builtin_bit_cast(bf16x8, a), __builtin_bit_cast(bf16x8, b), c, 0, 0, 0);
}
__device__ __forceinline__ f32x4 mfma_f16(half8 a, half8 b, f32x4 c) {
    return __builtin_amdgcn_mfma_f32_16x16x32_f16(a, b, c, 0, 0, 0);
}
__device__ __forceinline__ u32 pk_f16(float a, float b) {
    return __builtin_bit_cast(u32, __builtin_amdgcn_cvt_pkrtz(a, b));
}
__device__ __forceinline__ void gl_lds16(const void* g, void* l) {
    __builtin_amdgcn_global_load_lds(
        (const __attribute__((address_space(1))) u32*)g,
        (__attribute__((address_space(3))) u32*)l, 16, 0, 0);
}
// raw barrier / waitcnt: no compiler-inserted vmcnt(0) drain (prefetch stays in flight)
__device__ __forceinline__ void bar_raw() { asm volatile("s_barrier" ::: "memory"); }
__device__ __forceinline__ void wait_vm4() { asm volatile("s_waitcnt vmcnt(4)" ::: "memory"); }
__device__ __forceinline__ void wait_vm0() { asm volatile("s_waitcnt vmcnt(0)" ::: "memory"); }

// K-row permutation for flash: LDS row rc holds global k-row perm_inv(rc) so that
// PV A-frags are in-lane after S^T: k'(nt,quad,r)=32*(nt>>1)+8*quad+4*(nt&1)+r
__device__ __forceinline__ int perm_inv(int rc) {
    const int nt = rc >> 4, mid = (rc >> 2) & 3, r = rc & 3;
    return 32 * (nt >> 1) + 8 * mid + 4 * (nt & 1) + r;
}

// ---------- fused fp32 -> bf16 convert: x + Wq + Wk + Wv + Wo in one launch ----------
// float4-unit index space: x [0, 2097152), then 4 weights of 262144 each. Exact grid.
__global__ void cvt_all(const float4* __restrict__ x,  const float4* __restrict__ Wq,
                        const float4* __restrict__ Wk, const float4* __restrict__ Wv,
                        const float4* __restrict__ Wo,
                        uint2* __restrict__ oX, uint2* __restrict__ oWcat,
                        uint2* __restrict__ oWo) {
    const int i = blockIdx.x * 256 + threadIdx.x;
    const float4* in;
    uint2* out;
    if (i < 2097152) {
        in = x + i;  out = oX + i;
    } else {
        const int j = i - 2097152;
        const int w = j >> 18, k = j & 262143;
        in  = (w == 0 ? Wq : w == 1 ? Wk : w == 2 ? Wv : Wo) + k;
        out = (w < 3) ? (oWcat + w * 262144 + k) : (oWo + k);
    }
    float4 f = *in;
    uint2 o;
    o.x = (u32)f2bf(f.x) | ((u32)f2bf(f.y) << 16);
    o.y = (u32)f2bf(f.z) | ((u32)f2bf(f.w) << 16);
    *out = o;
}

// ---------- NT GEMM (R5 structure): C[m][n] = sum_k A[m][k]*W[n][k], K=1024 ----------
// BM=BN=128, BK=32. Double-buffered LDS, raw-barrier pipeline (no vmcnt(0) in loop).
// LDS XOR chunk swizzle: row r's chunk c at physical chunk c^((r>>1)&3) -> <=2-way banks.
// MODE 0: N=3072 fused QKV epilogue with RoPE on Q,K (applied to fp32 acc pre-quantize):
//         Q,K bf16 -> [BH][S][64], V fp16 -> transposed [BH][64][S]
// MODE 1: plain fp32 store
template <int MODE>
__global__ __launch_bounds__(256)
void gemm_nt(const u16* __restrict__ A, const u16* __restrict__ Bw,
             u16* __restrict__ oQ, u16* __restrict__ oK, u16* __restrict__ oVt,
             float* __restrict__ oF) {
    __shared__ u16 As[2][128 * 32];
    __shared__ u16 Bs[2][128 * 32];
    const int tid  = threadIdx.x;
    const int wave = tid >> 6, lane = tid & 63;
    const int quad = lane >> 4, l15 = lane & 15;
    const int wr = wave >> 1, wc = wave & 1;
    const int mbase = blockIdx.y * 128;
    const int nbase = blockIdx.x * 128;

    f32x4 acc[4][4];
#pragma unroll
    for (int i = 0; i < 4; i++)
#pragma unroll
        for (int j = 0; j < 4; j++) acc[i][j] = (f32x4)0.0f;

    // staging: physical chunk holds global chunk c = (lane&3)^((lane>>3)&3) of row srow
    const int srow0 = wave * 32 + (lane >> 2);
    const int srow1 = srow0 + 16;
    const int scolb = ((lane & 3) ^ ((lane >> 3) & 3)) * 16;
    const int ldsOff = wave * 2048 + lane * 16;         // bytes
    const u16* gA0 = A  + (size_t)(mbase + srow0) * KDIM;
    const u16* gA1 = A  + (size_t)(mbase + srow1) * KDIM;
    const u16* gB0 = Bw + (size_t)(nbase + srow0) * KDIM;
    const u16* gB1 = Bw + (size_t)(nbase + srow1) * KDIM;
    // fragment read: chunk quad of row R at physical chunk quad^((l15>>1)&3)
    const int koffq = (quad ^ ((l15 >> 1) & 3)) * 8;    // u16 units

    // prologue: stage tile 0 into buffer 0
    gl_lds16((const char*)gA0 + scolb, (char*)As[0] + ldsOff);
    gl_lds16((const char*)gA1 + scolb, (char*)As[0] + ldsOff + 1024);
    gl_lds16((const char*)gB0 + scolb, (char*)Bs[0] + ldsOff);
    gl_lds16((const char*)gB1 + scolb, (char*)Bs[0] + ldsOff + 1024);

    const int KT = KDIM / 32;
    for (int kt = 0; kt < KT; kt++) {
        const int cur = kt & 1, nxt = cur ^ 1;
        const int kkn = ((kt + 1 < KT) ? (kt + 1) : kt) * 32;
        bar_raw();   // (A) all waves done reading buf[nxt]
        gl_lds16((const char*)(gA0 + kkn) + scolb, (char*)As[nxt] + ldsOff);
        gl_lds16((const char*)(gA1 + kkn) + scolb, (char*)As[nxt] + ldsOff + 1024);
        gl_lds16((const char*)(gB0 + kkn) + scolb, (char*)Bs[nxt] + ldsOff);
        gl_lds16((const char*)(gB1 + kkn) + scolb, (char*)Bs[nxt] + ldsOff + 1024);
        wait_vm4();  // tile kt's 4 loads retired; prefetch still in flight
        bar_raw();   // (B) tile-kt staging visible to all waves

        short8 af[4], bf[4];
#pragma unroll
        for (int mt = 0; mt < 4; mt++)
            af[mt] = *(const short8*)&As[cur][(wr * 64 + mt * 16 + l15) * 32 + koffq];
#pragma unroll
        for (int nt = 0; nt < 4; nt++)
            bf[nt] = *(const short8*)&Bs[cur][(wc * 64 + nt * 16 + l15) * 32 + koffq];
#pragma unroll
        for (int mt = 0; mt < 4; mt++)
#pragma unroll
            for (int nt = 0; nt < 4; nt++)
                acc[mt][nt] = mfma_bf16(af[mt], bf[nt], acc[mt][nt]);
    }
    wait_vm0();   // drain dangling dummy prefetch

    // ---- epilogue. C layout: col = l15, row = quad*4 + reg ----
    const int proj_blk = (MODE == 0) ? (nbase >> 10) : 2;   // block-uniform: 0=Q 1=K 2=V

    // RoPE per-lane constants (Q/K blocks only): freq index i = nt*8 + (l15>>1)
    float fq[4], cf[4], sf[4];
    if (MODE == 0 && proj_blk < 2) {
#pragma unroll
        for (int nt = 0; nt < 4; nt++) {
            const float fi = __expf(-(float)(nt * 8 + (l15 >> 1)) * 0.287823136624255f);
            fq[nt] = fi;
            cf[nt] = cosf(fi);     // rotation-step constants (angle = fi, small)
            sf[nt] = sinf(fi);
        }
    }
    const int par = l15 & 1;   // 0: even d (e-slot), 1: odd d (o-slot)

#pragma unroll
    for (int mt = 0; mt < 4; mt++) {
#pragma unroll
        for (int nt = 0; nt < 4; nt++) {
            const int n  = nbase + wc * 64 + nt * 16 + l15;
            const int mb = mbase + wr * 64 + mt * 16 + quad * 4;
            f32x4 v = acc[mt][nt];
            if (MODE == 0) {
                const int e = n & 1023;
                const int h = e >> 6, d = e & 63;
                if (proj_blk == 2) {
                    const int b_ = mb >> 11, s = mb & 2047;
                    const int bh = b_ * NHEAD + h;
                    uint2 pk;                           // fp16 V (RTZ)
                    pk.x = pk_f16(v[0], v[1]);
                    pk.y = pk_f16(v[2], v[3]);
                    *(uint2*)&oVt[((size_t)bh * DK + d) * S_LEN + s] = pk;
                } else {
                    u16* dst = (proj_blk == 0) ? oQ : oK;
                    // partner values (d^1 lives in lane^1)
                    float vp[4];
#pragma unroll
                    for (int r = 0; r < 4; r++) vp[r] = __shfl_xor(v[r], 1);
                    // sincos at base token, then rotate by f per r-step
                    const int b_ = mb >> 11, s0 = mb & 2047;
                    const int bh = b_ * NHEAD + h;
                    float cc = cosf((float)s0 * fq[nt]);
                    float ss = sinf((float)s0 * fq[nt]);
#pragma unroll
                    for (int r = 0; r < 4; r++) {
                        const float res = par ? (vp[r] * ss + v[r] * cc)
                                              : (v[r] * cc - vp[r] * ss);
                        dst[((size_t)bh * S_LEN + (s0 + r)) * DK + d] = f2bf(res);
                        const float c2 = cc * cf[nt] - ss * sf[nt];
                        ss = ss * cf[nt] + cc * sf[nt];
                        cc = c2;
                    }
                }
            } else {
#pragma unroll
                for (int r = 0; r < 4; r++)
                    oF[(size_t)(mb + r) * DM + n] = v[r];
            }
        }
    }
}

// ---------- causal flash attention (S^T form, P in-register, double-buffered pipeline) ----------
// grid (BH=64, 32): bh = blockIdx.x so all 32 q-blocks of a head share an XCD
// (id mod 8 == bh mod 8); qt = 31-blockIdx.y (heavy tiles dispatch first).
__global__ __launch_bounds__(256)
void flash_attn(const u16* __restrict__ Q, const u16* __restrict__ K,
                const u16* __restrict__ Vt, u16* __restrict__ Oc) {
    __shared__ u16 Ks[2][64 * 64];     // permuted k-rows, XOR chunk swizzle
    __shared__ u16 Vs[2][64 * 64];     // [d][s], XOR chunk swizzle
    const int qt = 31 - (int)blockIdx.y;
    const int bh = blockIdx.x;
    const int tid  = threadIdx.x;
    const int wave = tid >> 6, lane = tid & 63;
    const int quad = lane >> 4, l15 = lane & 15;
    const int x7 = l15 & 7;
    const size_t headQK = (size_t)bh * S_LEN * DK;
    const size_t headVt = (size_t)bh * DK * S_LEN;
    const int b = bh >> 4, h = bh & 15;
    const float SCL = 0.18033688011112042f;   // (1/8) * log2(e)

    half8 ones;
#pragma unroll
    for (int j = 0; j < 8; j++) ones[j] = (_Float16)1.0f;

    const int rwl  = lane >> 3;                 // row within 8-row slab
    const int scol = (lane & 7) ^ rwl;          // XOR-swizzled chunk column
    const int rc0 = wave * 16 + rwl, rc1 = rc0 + 8;
    const u16* gK0 = K  + headQK + (size_t)perm_inv(rc0) * DK + scol * 8;
    const u16* gK1 = K  + headQK + (size_t)perm_inv(rc1) * DK + scol * 8;
    const u16* gV0 = Vt + headVt + (size_t)rc0 * S_LEN + scol * 8;
    const u16* gV1 = Vt + headVt + (size_t)rc1 * S_LEN + scol * 8;
    const int ldsOff = wave * 2048 + lane * 16;
    const int koff0 = (quad ^ x7) * 8;          // dk chunk 0..31, swizzled
    const int koff1 = ((4 + quad) ^ x7) * 8;    // dk chunk 32..63

    // Q B-fragments
    const int qrow = qt * 64 + wave * 16 + l15;
    const short8 qf0 = *(const short8*)&Q[headQK + (size_t)qrow * DK + quad * 8];
    const short8 qf1 = *(const short8*)&Q[headQK + (size_t)qrow * DK + 32 + quad * 8];

    float m_st = -__builtin_inff();
    f32x4 lacc = (f32x4)0.0f;
    f32x4 oacc[4];
#pragma unroll
    for (int n = 0; n < 4; n++) oacc[n] = (f32x4)0.0f;

    // prologue: stage tile 0 into buffer 0
    gl_lds16(gK0, (char*)Ks[0] + ldsOff);
    gl_lds16(gK1, (char*)Ks[0] + ldsOff + 1024);
    gl_lds16(gV0, (char*)Vs[0] + ldsOff);
    gl_lds16(gV1, (char*)Vs[0] + ldsOff + 1024);

    for (int kt = 0; kt <= qt; kt++) {
        const int cur = kt & 1, nxt = cur ^ 1;
        bar_raw();   // (A) everyone done reading buf[nxt]
        {            // prefetch tile kt+1 (clamped dummy on last iter)
            const int ktn = (kt < qt) ? kt + 1 : qt;
            gl_lds16(gK0 + (size_t)ktn * 64 * DK, (char*)Ks[nxt] + ldsOff);
            gl_lds16(gK1 + (size_t)ktn * 64 * DK, (char*)Ks[nxt] + ldsOff + 1024);
            gl_lds16(gV0 + ktn * 64,              (char*)Vs[nxt] + ldsOff);
            gl_lds16(gV1 + ktn * 64,              (char*)Vs[nxt] + ldsOff + 1024);
        }
        wait_vm4();  // tile kt landed; prefetch stays in flight
        bar_raw();   // (B) all waves' tile-kt staging visible

        // S^T scores (log2-scaled): A = K_perm rows, B = Q
        f32x4 sc[4];
#pragma unroll
        for (int nt = 0; nt < 4; nt++) {
            const int rb = (nt * 16 + l15) * 64;
            short8 kf0 = *(const short8*)&Ks[cur][rb + koff0];
            short8 kf1 = *(const short8*)&Ks[cur][rb + koff1];
            f32x4 z = (f32x4)0.0f;
            z = mfma_bf16(kf0, qf0, z);
            z = mfma_bf16(kf1, qf1, z);
#pragma unroll
            for (int r = 0; r < 4; r++) z[r] *= SCL;
            sc[nt] = z;
        }
        if (kt == qt) {   // diagonal tile causal mask: k' > wave*16 + l15
            const int qloc = wave * 16 + l15;
#pragma unroll
            for (int nt = 0; nt < 4; nt++) {
                const int kb = 32 * (nt >> 1) + 8 * quad + 4 * (nt & 1);
#pragma unroll
                for (int r = 0; r < 4; r++)
                    if (kb + r > qloc) sc[nt][r] = -__builtin_inff();
            }
        }
        // row max: in-lane over 16, then across quads
        float mx0 = fmaxf(fmaxf(sc[0][0], sc[0][1]), fmaxf(sc[0][2], sc[0][3]));
        float mx1 = fmaxf(fmaxf(sc[1][0], sc[1][1]), fmaxf(sc[1][2], sc[1][3]));
        float mx2 = fmaxf(fmaxf(sc[2][0], sc[2][1]), fmaxf(sc[2][2], sc[2][3]));
        float mx3 = fmaxf(fmaxf(sc[3][0], sc[3][1]), fmaxf(sc[3][2], sc[3][3]));
        float mx = fmaxf(fmaxf(mx0, mx1), fmaxf(mx2, mx3));
        mx = fmaxf(mx, __shfl_xor(mx, 16));
        mx = fmaxf(mx, __shfl_xor(mx, 32));
        const float mn = fmaxf(m_st, mx);
        const float alpha = __builtin_amdgcn_exp2f(m_st - mn);
        m_st = mn;
        // P = exp2(sc - m): in-place, then pack to fp16 A-frags (in-lane)
#pragma unroll
        for (int nt = 0; nt < 4; nt++)
#pragma unroll
            for (int r = 0; r < 4; r++)
                sc[nt][r] = __builtin_amdgcn_exp2f(sc[nt][r] - m_st);
        u32 pw[8];
        pw[0] = pk_f16(sc[0][0], sc[0][1]); pw[1] = pk_f16(sc[0][2], sc[0][3]);
        pw[2] = pk_f16(sc[1][0], sc[1][1]); pw[3] = pk_f16(sc[1][2], sc[1][3]);
        pw[4] = pk_f16(sc[2][0], sc[2][1]); pw[5] = pk_f16(sc[2][2], sc[2][3]);
        pw[6] = pk_f16(sc[3][0], sc[3][1]); pw[7] = pk_f16(sc[3][2], sc[3][3]);
        half8 pf0 = __builtin_bit_cast(half8, *(uint4*)&pw[0]);
        half8 pf1 = __builtin_bit_cast(half8, *(uint4*)&pw[4]);
        // alpha broadcast for C-layout rows quad*4+r (src lane = quad*16 + quad*4+r)
        float alr[4];
#pragma unroll
        for (int r = 0; r < 4; r++) alr[r] = __shfl(alpha, quad * 20 + r);
#pragma unroll
        for (int n = 0; n < 4; n++)
#pragma unroll
            for (int r = 0; r < 4; r++) oacc[n][r] *= alr[r];
#pragma unroll
        for (int r = 0; r < 4; r++) lacc[r] *= alr[r];
        // PV + row-sum (fp16)
#pragma unroll
        for (int c = 0; c < 2; c++) {
            const half8 pf = c ? pf1 : pf0;
            lacc = mfma_f16(pf, ones, lacc);
            const int voff = ((c * 4 + quad) ^ x7) * 8;
#pragma unroll
            for (int nt2 = 0; nt2 < 4; nt2++) {
                half8 vf = __builtin_bit_cast(half8,
                    *(const short8*)&Vs[cur][(nt2 * 16 + l15) * 64 + voff]);
                oacc[nt2] = mfma_f16(pf, vf, oacc[nt2]);
            }
        }
    }
    wait_vm0();   // drain dangling dummy prefetch before exit

    // epilogue: rows quad*4+r, cols l15
#pragma unroll
    for (int r = 0; r < 4; r++) {
        const float inv = 1.0f / lacc[r];
        const int s = qt * 64 + wave * 16 + quad * 4 + r;
#pragma unroll
        for (int nt2 = 0; nt2 < 4; nt2++)
            Oc[((size_t)(b * S_LEN + s)) * DM + h * 64 + nt2 * 16 + l15] =
                f2bf(oacc[nt2][r] * inv);
    }
}

// ---------- workspace layout (u16 elements) ----------
#define OFF_XBF  ((size_t)0)
#define OFF_WCAT ((size_t)8388608)
#define OFF_WO   ((size_t)11534336)
#define OFF_QB   ((size_t)12582912)
#define OFF_KB   ((size_t)20971520)
#define OFF_VT   ((size_t)29360128)

extern "C" void kernel_launch(void* const* d_in, const int* in_sizes, int n_in,
                              void* d_out, int out_size, void* d_ws, size_t ws_size,
                              hipStream_t stream) {
    const float* x  = (const float*)d_in[0];
    const float* Wq = (const float*)d_in[1];
    const float* Wk = (const float*)d_in[2];
    const float* Wv = (const float*)d_in[3];
    const float* Wo = (const float*)d_in[4];
    u16* ws  = (u16*)d_ws;
    u16* XBF = ws + OFF_XBF;
    u16* WCA = ws + OFF_WCAT;
    u16* WOB = ws + OFF_WO;
    u16* QB  = ws + OFF_QB;
    u16* KB  = ws + OFF_KB;
    u16* VT  = ws + OFF_VT;
    u16* AT  = XBF;   // reuse

    cvt_all<<<12288, 256, 0, stream>>>((const float4*)x, (const float4*)Wq,
                                       (const float4*)Wk, (const float4*)Wv,
                                       (const float4*)Wo,
                                       (uint2*)XBF, (uint2*)WCA, (uint2*)WOB);

    gemm_nt<0><<<dim3(24, 64), 256, 0, stream>>>(XBF, WCA, QB, KB, VT, nullptr);
    flash_attn<<<dim3(64, 32), 256, 0, stream>>>(QB, KB, VT, AT);
    gemm_nt<1><<<dim3(8, 64), 256, 0, stream>>>(AT, WOB, nullptr, nullptr, nullptr,
                                                (float*)d_out);
}

// Round 9
// 269.427 us; speedup vs baseline: 1.5744x; 1.0290x over previous
//
#include <hip/hip_runtime.h>

typedef unsigned short u16;
typedef unsigned int   u32;

typedef short    short8 __attribute__((ext_vector_type(8)));
typedef __bf16   bf16x8 __attribute__((ext_vector_type(8)));
typedef _Float16 half8  __attribute__((ext_vector_type(8)));
typedef float    f32x4  __attribute__((ext_vector_type(4)));

#define S_LEN   2048
#define DM      1024
#define NHEAD   16
#define DK      64
#define BH_TOT  64
#define M_TOK   8192
#define KDIM    1024

// ---------- helpers ----------
__device__ __forceinline__ u16 f2bf(float f) {
    u32 u = __builtin_bit_cast(u32, f);
    u += 0x7FFFu + ((u >> 16) & 1u);      // RNE
    return (u16)(u >> 16);
}
__device__ __forceinline__ f32x4 mfma_bf16(short8 a, short8 b, f32x4 c) {
    return __builtin_amdgcn_mfma_f32_16x16x32_bf16(
        __builtin_bit_cast(bf16x8, a), __builtin_bit_cast(bf16x8, b), c, 0, 0, 0);
}
__device__ __forceinline__ f32x4 mfma_f16(half8 a, half8 b, f32x4 c) {
    return __builtin_amdgcn_mfma_f32_16x16x32_f16(a, b, c, 0, 0, 0);
}
__device__ __forceinline__ u32 pk_f16(float a, float b) {
    return __builtin_bit_cast(u32, __builtin_amdgcn_cvt_pkrtz(a, b));
}
__device__ __forceinline__ void gl_lds16(const void* g, void* l) {
    __builtin_amdgcn_global_load_lds(
        (const __attribute__((address_space(1))) u32*)g,
        (__attribute__((address_space(3))) u32*)l, 16, 0, 0);
}
// raw barrier / waitcnt: no compiler-inserted vmcnt(0) drain (prefetch stays in flight)
__device__ __forceinline__ void bar_raw() { asm volatile("s_barrier" ::: "memory"); }
__device__ __forceinline__ void wait_vm4() { asm volatile("s_waitcnt vmcnt(4)" ::: "memory"); }
__device__ __forceinline__ void wait_vm0() { asm volatile("s_waitcnt vmcnt(0)" ::: "memory"); }

// K-row permutation for flash: LDS row rc holds global k-row perm_inv(rc) so that
// PV A-frags are in-lane after S^T: k'(nt,quad,r)=32*(nt>>1)+8*quad+4*(nt&1)+r
__device__ __forceinline__ int perm_inv(int rc) {
    const int nt = rc >> 4, mid = (rc >> 2) & 3, r = rc & 3;
    return 32 * (nt >> 1) + 8 * mid + 4 * (nt & 1) + r;
}

// ---------- fused fp32->bf16 convert + RoPE table build ----------
// blocks [0,12288): cvt of x/Wq/Wk/Wv/Wo (float4 units). blocks [12288,12544):
// sin/cos table [i][s] fp32 (i=freq 0..31, s=0..2047), fp32 angles like the reference.
__global__ void cvt_all(const float4* __restrict__ x,  const float4* __restrict__ Wq,
                        const float4* __restrict__ Wk, const float4* __restrict__ Wv,
                        const float4* __restrict__ Wo,
                        uint2* __restrict__ oX, uint2* __restrict__ oWcat,
                        uint2* __restrict__ oWo,
                        float* __restrict__ sT, float* __restrict__ cT) {
    const int i = blockIdx.x * 256 + threadIdx.x;
    if (i < 3145728) {
        const float4* in;
        uint2* out;
        if (i < 2097152) {
            in = x + i;  out = oX + i;
        } else {
            const int j = i - 2097152;
            const int w = j >> 18, k = j & 262143;
            in  = (w == 0 ? Wq : w == 1 ? Wk : w == 2 ? Wv : Wo) + k;
            out = (w < 3) ? (oWcat + w * 262144 + k) : (oWo + k);
        }
        float4 f = *in;
        uint2 o;
        o.x = (u32)f2bf(f.x) | ((u32)f2bf(f.y) << 16);
        o.y = (u32)f2bf(f.z) | ((u32)f2bf(f.w) << 16);
        *out = o;
    } else {
        const int idx = i - 3145728;            // [0, 65536): i=idx>>11, s=idx&2047
        const float fi = expf(-(float)(idx >> 11) * 0.287823136624255f);
        const float ang = (float)(idx & 2047) * fi;
        sT[idx] = sinf(ang);
        cT[idx] = cosf(ang);
    }
}

// ---------- NT GEMM (R5 structure): C[m][n] = sum_k A[m][k]*W[n][k], K=1024 ----------
// BM=BN=128, BK=32. Double-buffered LDS, raw-barrier pipeline (no vmcnt(0) in loop).
// LDS XOR chunk swizzle: row r's chunk c at physical chunk c^((r>>1)&3) -> <=2-way banks.
// MODE 0: N=3072 fused QKV epilogue with table-based RoPE on Q,K (fp32 acc pre-quantize):
//         Q,K bf16 -> [BH][S][64], V fp16 -> transposed [BH][64][S]
// MODE 1: plain fp32 store
template <int MODE>
__global__ __launch_bounds__(256)
void gemm_nt(const u16* __restrict__ A, const u16* __restrict__ Bw,
             u16* __restrict__ oQ, u16* __restrict__ oK, u16* __restrict__ oVt,
             float* __restrict__ oF,
             const float* __restrict__ ropeS, const float* __restrict__ ropeC) {
    __shared__ u16 As[2][128 * 32];
    __shared__ u16 Bs[2][128 * 32];
    const int tid  = threadIdx.x;
    const int wave = tid >> 6, lane = tid & 63;
    const int quad = lane >> 4, l15 = lane & 15;
    const int wr = wave >> 1, wc = wave & 1;
    const int mbase = blockIdx.y * 128;
    const int nbase = blockIdx.x * 128;

    f32x4 acc[4][4];
#pragma unroll
    for (int i = 0; i < 4; i++)
#pragma unroll
        for (int j = 0; j < 4; j++) acc[i][j] = (f32x4)0.0f;

    // staging: physical chunk holds global chunk c = (lane&3)^((lane>>3)&3) of row srow
    const int srow0 = wave * 32 + (lane >> 2);
    const int srow1 = srow0 + 16;
    const int scolb = ((lane & 3) ^ ((lane >> 3) & 3)) * 16;
    const int ldsOff = wave * 2048 + lane * 16;         // bytes
    const u16* gA0 = A  + (size_t)(mbase + srow0) * KDIM;
    const u16* gA1 = A  + (size_t)(mbase + srow1) * KDIM;
    const u16* gB0 = Bw + (size_t)(nbase + srow0) * KDIM;
    const u16* gB1 = Bw + (size_t)(nbase + srow1) * KDIM;
    // fragment read: chunk quad of row R at physical chunk quad^((l15>>1)&3)
    const int koffq = (quad ^ ((l15 >> 1) & 3)) * 8;    // u16 units

    // prologue: stage tile 0 into buffer 0
    gl_lds16((const char*)gA0 + scolb, (char*)As[0] + ldsOff);
    gl_lds16((const char*)gA1 + scolb, (char*)As[0] + ldsOff + 1024);
    gl_lds16((const char*)gB0 + scolb, (char*)Bs[0] + ldsOff);
    gl_lds16((const char*)gB1 + scolb, (char*)Bs[0] + ldsOff + 1024);

    const int KT = KDIM / 32;
    for (int kt = 0; kt < KT; kt++) {
        const int cur = kt & 1, nxt = cur ^ 1;
        const int kkn = ((kt + 1 < KT) ? (kt + 1) : kt) * 32;
        bar_raw();   // (A) all waves done reading buf[nxt]
        gl_lds16((const char*)(gA0 + kkn) + scolb, (char*)As[nxt] + ldsOff);
        gl_lds16((const char*)(gA1 + kkn) + scolb, (char*)As[nxt] + ldsOff + 1024);
        gl_lds16((const char*)(gB0 + kkn) + scolb, (char*)Bs[nxt] + ldsOff);
        gl_lds16((const char*)(gB1 + kkn) + scolb, (char*)Bs[nxt] + ldsOff + 1024);
        wait_vm4();  // tile kt's 4 loads retired; prefetch still in flight
        bar_raw();   // (B) tile-kt staging visible to all waves

        short8 af[4], bf[4];
#pragma unroll
        for (int mt = 0; mt < 4; mt++)
            af[mt] = *(const short8*)&As[cur][(wr * 64 + mt * 16 + l15) * 32 + koffq];
#pragma unroll
        for (int nt = 0; nt < 4; nt++)
            bf[nt] = *(const short8*)&Bs[cur][(wc * 64 + nt * 16 + l15) * 32 + koffq];
#pragma unroll
        for (int mt = 0; mt < 4; mt++)
#pragma unroll
            for (int nt = 0; nt < 4; nt++)
                acc[mt][nt] = mfma_bf16(af[mt], bf[nt], acc[mt][nt]);
    }
    wait_vm0();   // drain dangling dummy prefetch

    // ---- epilogue. C layout: col = l15, row = quad*4 + reg ----
    const int proj_blk = (MODE == 0) ? (nbase >> 10) : 2;   // block-uniform: 0=Q 1=K 2=V

    const float* sB[4];
    const float* cB[4];
    if (MODE == 0 && proj_blk < 2) {
#pragma unroll
        for (int nt = 0; nt < 4; nt++) {
            const int fi = nt * 8 + (l15 >> 1);
            sB[nt] = ropeS + fi * 2048;
            cB[nt] = ropeC + fi * 2048;
        }
    }
    const int par = l15 & 1;   // 0: even d (e-slot), 1: odd d (o-slot)

#pragma unroll
    for (int mt = 0; mt < 4; mt++) {
#pragma unroll
        for (int nt = 0; nt < 4; nt++) {
            const int n  = nbase + wc * 64 + nt * 16 + l15;
            const int mb = mbase + wr * 64 + mt * 16 + quad * 4;
            f32x4 v = acc[mt][nt];
            if (MODE == 0) {
                const int e = n & 1023;
                const int h = e >> 6, d = e & 63;
                if (proj_blk == 2) {
                    const int b_ = mb >> 11, s = mb & 2047;
                    const int bh = b_ * NHEAD + h;
                    uint2 pk;                           // fp16 V (RTZ)
                    pk.x = pk_f16(v[0], v[1]);
                    pk.y = pk_f16(v[2], v[3]);
                    *(uint2*)&oVt[((size_t)bh * DK + d) * S_LEN + s] = pk;
                } else {
                    u16* dst = (proj_blk == 0) ? oQ : oK;
                    // partner values (d^1 lives in lane^1)
                    float vp[4];
#pragma unroll
                    for (int r = 0; r < 4; r++) vp[r] = __shfl_xor(v[r], 1);
                    const int b_ = mb >> 11, s0 = mb & 2047;
                    const int bh = b_ * NHEAD + h;
                    const f32x4 sn = *(const f32x4*)(sB[nt] + s0);   // s0 % 4 == 0
                    const f32x4 cs = *(const f32x4*)(cB[nt] + s0);
#pragma unroll
                    for (int r = 0; r < 4; r++) {
                        const float res = par ? (vp[r] * sn[r] + v[r] * cs[r])
                                              : (v[r] * cs[r] - vp[r] * sn[r]);
                        dst[((size_t)bh * S_LEN + (s0 + r)) * DK + d] = f2bf(res);
                    }
                }
            } else {
#pragma unroll
                for (int r = 0; r < 4; r++)
                    oF[(size_t)(mb + r) * DM + n] = v[r];
            }
        }
    }
}

// ---------- causal flash attention: 128-row Q-tiles, S^T form, P in-register ----------
// grid (BH=64, 16): bh = blockIdx.x (XCD-local per head), qt = 15-blockIdx.y (heavy first).
// Block covers q rows [qt*128, qt*128+128); each wave owns two 16-row halves (h=0: rows
// +wave*16, h=1: rows +64+wave*16) sharing the K/V LDS tiles -> two independent
// QK/softmax/PV chains per iteration fill latency gaps; barrier count per work halved.
// Iterations kt=0..2qt+1 over 64-col k-tiles; half h's diagonal at kt==2qt+h; half 0
// skips kt==2qt+1 (fully masked).
__global__ __launch_bounds__(256)
void flash_attn(const u16* __restrict__ Q, const u16* __restrict__ K,
                const u16* __restrict__ Vt, u16* __restrict__ Oc) {
    __shared__ u16 Ks[2][64 * 64];     // permuted k-rows, XOR chunk swizzle
    __shared__ u16 Vs[2][64 * 64];     // [d][s], XOR chunk swizzle
    const int qt = 15 - (int)blockIdx.y;
    const int bh = blockIdx.x;
    const int tid  = threadIdx.x;
    const int wave = tid >> 6, lane = tid & 63;
    const int quad = lane >> 4, l15 = lane & 15;
    const int x7 = l15 & 7;
    const size_t headQK = (size_t)bh * S_LEN * DK;
    const size_t headVt = (size_t)bh * DK * S_LEN;
    const int b = bh >> 4, h = bh & 15;
    const float SCL = 0.18033688011112042f;   // (1/8) * log2(e)

    half8 ones;
#pragma unroll
    for (int j = 0; j < 8; j++) ones[j] = (_Float16)1.0f;

    const int rwl  = lane >> 3;                 // row within 8-row slab
    const int scol = (lane & 7) ^ rwl;          // XOR-swizzled chunk column
    const int rc0 = wave * 16 + rwl, rc1 = rc0 + 8;
    const u16* gK0 = K  + headQK + (size_t)perm_inv(rc0) * DK + scol * 8;
    const u16* gK1 = K  + headQK + (size_t)perm_inv(rc1) * DK + scol * 8;
    const u16* gV0 = Vt + headVt + (size_t)rc0 * S_LEN + scol * 8;
    const u16* gV1 = Vt + headVt + (size_t)rc1 * S_LEN + scol * 8;
    const int ldsOff = wave * 2048 + lane * 16;
    const int koff0 = (quad ^ x7) * 8;          // dk chunk 0..31, swizzled
    const int koff1 = ((4 + quad) ^ x7) * 8;    // dk chunk 32..63

    // Q B-fragments for both halves
    short8 qf[2][2];
#pragma unroll
    for (int hh = 0; hh < 2; hh++) {
        const int qrow = qt * 128 + hh * 64 + wave * 16 + l15;
        qf[hh][0] = *(const short8*)&Q[headQK + (size_t)qrow * DK + quad * 8];
        qf[hh][1] = *(const short8*)&Q[headQK + (size_t)qrow * DK + 32 + quad * 8];
    }

    float m_st[2];
    f32x4 lacc[2];
    f32x4 oacc[2][4];
#pragma unroll
    for (int hh = 0; hh < 2; hh++) {
        m_st[hh] = -__builtin_inff();
        lacc[hh] = (f32x4)0.0f;
#pragma unroll
        for (int n = 0; n < 4; n++) oacc[hh][n] = (f32x4)0.0f;
    }

    const int NT = 2 * qt + 2;
    // prologue: stage tile 0 into buffer 0
    gl_lds16(gK0, (char*)Ks[0] + ldsOff);
    gl_lds16(gK1, (char*)Ks[0] + ldsOff + 1024);
    gl_lds16(gV0, (char*)Vs[0] + ldsOff);
    gl_lds16(gV1, (char*)Vs[0] + ldsOff + 1024);

    for (int kt = 0; kt < NT; kt++) {
        const int cur = kt & 1, nxt = cur ^ 1;
        bar_raw();   // (A) everyone done reading buf[nxt]
        {            // prefetch tile kt+1 (clamped dummy on last iter)
            const int ktn = (kt + 1 < NT) ? kt + 1 : kt;
            gl_lds16(gK0 + (size_t)ktn * 64 * DK, (char*)Ks[nxt] + ldsOff);
            gl_lds16(gK1 + (size_t)ktn * 64 * DK, (char*)Ks[nxt] + ldsOff + 1024);
            gl_lds16(gV0 + ktn * 64,              (char*)Vs[nxt] + ldsOff);
            gl_lds16(gV1 + ktn * 64,              (char*)Vs[nxt] + ldsOff + 1024);
        }
        wait_vm4();  // tile kt landed; prefetch stays in flight
        bar_raw();   // (B) all waves' tile-kt staging visible

#pragma unroll
        for (int hh = 0; hh < 2; hh++) {
            if (hh == 0 && kt == 2 * qt + 1) continue;   // fully masked for half 0
            // S^T scores (log2-scaled): A = K_perm rows, B = Q[hh]
            f32x4 sc[4];
#pragma unroll
            for (int nt = 0; nt < 4; nt++) {
                const int rb = (nt * 16 + l15) * 64;
                short8 kf0 = *(const short8*)&Ks[cur][rb + koff0];
                short8 kf1 = *(const short8*)&Ks[cur][rb + koff1];
                f32x4 z = (f32x4)0.0f;
                z = mfma_bf16(kf0, qf[hh][0], z);
                z = mfma_bf16(kf1, qf[hh][1], z);
#pragma unroll
                for (int r = 0; r < 4; r++) z[r] *= SCL;
                sc[nt] = z;
            }
            if (kt == 2 * qt + hh) {   // diagonal tile: local k' > wave*16 + l15
                const int qloc = wave * 16 + l15;
#pragma unroll
                for (int nt = 0; nt < 4; nt++) {
                    const int kb = 32 * (nt >> 1) + 8 * quad + 4 * (nt & 1);
#pragma unroll
                    for (int r = 0; r < 4; r++)
                        if (kb + r > qloc) sc[nt][r] = -__builtin_inff();
                }
            }
            // row max: in-lane over 16, then across quads
            float mx0 = fmaxf(fmaxf(sc[0][0], sc[0][1]), fmaxf(sc[0][2], sc[0][3]));
            float mx1 = fmaxf(fmaxf(sc[1][0], sc[1][1]), fmaxf(sc[1][2], sc[1][3]));
            float mx2 = fmaxf(fmaxf(sc[2][0], sc[2][1]), fmaxf(sc[2][2], sc[2][3]));
            float mx3 = fmaxf(fmaxf(sc[3][0], sc[3][1]), fmaxf(sc[3][2], sc[3][3]));
            float mx = fmaxf(fmaxf(mx0, mx1), fmaxf(mx2, mx3));
            mx = fmaxf(mx, __shfl_xor(mx, 16));
            mx = fmaxf(mx, __shfl_xor(mx, 32));
            const float mn = fmaxf(m_st[hh], mx);
            const float alpha = __builtin_amdgcn_exp2f(m_st[hh] - mn);
            m_st[hh] = mn;
            // P = exp2(sc - m): in-place, then pack to fp16 A-frags (in-lane)
#pragma unroll
            for (int nt = 0; nt < 4; nt++)
#pragma unroll
                for (int r = 0; r < 4; r++)
                    sc[nt][r] = __builtin_amdgcn_exp2f(sc[nt][r] - m_st[hh]);
            u32 pw[8];
            pw[0] = pk_f16(sc[0][0], sc[0][1]); pw[1] = pk_f16(sc[0][2], sc[0][3]);
            pw[2] = pk_f16(sc[1][0], sc[1][1]); pw[3] = pk_f16(sc[1][2], sc[1][3]);
            pw[4] = pk_f16(sc[2][0], sc[2][1]); pw[5] = pk_f16(sc[2][2], sc[2][3]);
            pw[6] = pk_f16(sc[3][0], sc[3][1]); pw[7] = pk_f16(sc[3][2], sc[3][3]);
            half8 pf0 = __builtin_bit_cast(half8, *(uint4*)&pw[0]);
            half8 pf1 = __builtin_bit_cast(half8, *(uint4*)&pw[4]);
            // alpha broadcast for C-layout rows quad*4+r (src lane = quad*16 + quad*4+r)
            float alr[4];
#pragma unroll
            for (int r = 0; r < 4; r++) alr[r] = __shfl(alpha, quad * 20 + r);
#pragma unroll
            for (int n = 0; n < 4; n++)
#pragma unroll
                for (int r = 0; r < 4; r++) oacc[hh][n][r] *= alr[r];
#pragma unroll
            for (int r = 0; r < 4; r++) lacc[hh][r] *= alr[r];
            // PV + row-sum (fp16)
#pragma unroll
            for (int c = 0; c < 2; c++) {
                const half8 pf = c ? pf1 : pf0;
                lacc[hh] = mfma_f16(pf, ones, lacc[hh]);
                const int voff = ((c * 4 + quad) ^ x7) * 8;
#pragma unroll
                for (int nt2 = 0; nt2 < 4; nt2++) {
                    half8 vf = __builtin_bit_cast(half8,
                        *(const short8*)&Vs[cur][(nt2 * 16 + l15) * 64 + voff]);
                    oacc[hh][nt2] = mfma_f16(pf, vf, oacc[hh][nt2]);
                }
            }
        }
    }
    wait_vm0();   // drain dangling dummy prefetch before exit

    // epilogue: rows quad*4+r, cols l15, both halves
#pragma unroll
    for (int hh = 0; hh < 2; hh++) {
#pragma unroll
        for (int r = 0; r < 4; r++) {
            const float inv = 1.0f / lacc[hh][r];
            const int s = qt * 128 + hh * 64 + wave * 16 + quad * 4 + r;
#pragma unroll
            for (int nt2 = 0; nt2 < 4; nt2++)
                Oc[((size_t)(b * S_LEN + s)) * DM + h * 64 + nt2 * 16 + l15] =
                    f2bf(oacc[hh][nt2][r] * inv);
        }
    }
}

// ---------- workspace layout (u16 elements) ----------
#define OFF_XBF   ((size_t)0)
#define OFF_WCAT  ((size_t)8388608)
#define OFF_WO    ((size_t)11534336)
#define OFF_QB    ((size_t)12582912)
#define OFF_KB    ((size_t)20971520)
#define OFF_VT    ((size_t)29360128)
#define OFF_ROPE  ((size_t)37748736)   // 65536 fp32 sin + 65536 fp32 cos = 512 KB

extern "C" void kernel_launch(void* const* d_in, const int* in_sizes, int n_in,
                              void* d_out, int out_size, void* d_ws, size_t ws_size,
                              hipStream_t stream) {
    const float* x  = (const float*)d_in[0];
    const float* Wq = (const float*)d_in[1];
    const float* Wk = (const float*)d_in[2];
    const float* Wv = (const float*)d_in[3];
    const float* Wo = (const float*)d_in[4];
    u16* ws  = (u16*)d_ws;
    u16* XBF = ws + OFF_XBF;
    u16* WCA = ws + OFF_WCAT;
    u16* WOB = ws + OFF_WO;
    u16* QB  = ws + OFF_QB;
    u16* KB  = ws + OFF_KB;
    u16* VT  = ws + OFF_VT;
    float* ropeS = (float*)(ws + OFF_ROPE);
    float* ropeC = ropeS + 65536;
    u16* AT  = XBF;   // reuse

    cvt_all<<<12544, 256, 0, stream>>>((const float4*)x, (const float4*)Wq,
                                       (const float4*)Wk, (const float4*)Wv,
                                       (const float4*)Wo,
                                       (uint2*)XBF, (uint2*)WCA, (uint2*)WOB,
                                       ropeS, ropeC);

    gemm_nt<0><<<dim3(24, 64), 256, 0, stream>>>(XBF, WCA, QB, KB, VT, nullptr,
                                                 ropeS, ropeC);
    flash_attn<<<dim3(64, 16), 256, 0, stream>>>(QB, KB, VT, AT);
    gemm_nt<1><<<dim3(8, 64), 256, 0, stream>>>(AT, WOB, nullptr, nullptr, nullptr,
                                                (float*)d_out, nullptr, nullptr);
}